// Round 6
// baseline (139.122 us; speedup 1.0000x reference)
//
#include <hip/hip_runtime.h>
#include <math.h>

#define EPSF 1e-6f

typedef __attribute__((ext_vector_type(8))) short bf16x8;   // 8 bf16 = 4 VGPR (MFMA A/B frag)
typedef __attribute__((ext_vector_type(4))) float f32x4;    // MFMA C/D frag
typedef __attribute__((ext_vector_type(4))) unsigned short u16x4;
typedef __attribute__((ext_vector_type(8))) unsigned short u16x8;

constexpr int TT = 256, MT = 2000, NP = 7200;

static __device__ __forceinline__ unsigned short f2bf(float f) {
    unsigned int u = __float_as_uint(f);
    u += 0x7FFFu + ((u >> 16) & 1u);
    return (unsigned short)(u >> 16);
}
static __device__ __forceinline__ float frcp(float x) { return __builtin_amdgcn_rcpf(x); }

// ---------------- Kernel 1: fused prep ----------------
__global__ __launch_bounds__(256) void prep_kernel(const float* __restrict__ logits,
                                                   const float* __restrict__ lab,
                                                   unsigned short* __restrict__ probs,
                                                   unsigned short* __restrict__ nlab) {
    int b = blockIdx.x;
    if (b < 900) {
        int i = (b * 256 + threadIdx.x) * 8;
        float4 x0 = *reinterpret_cast<const float4*>(logits + i);
        float4 x1 = *reinterpret_cast<const float4*>(logits + i + 4);
        float v[8] = {x0.x, x0.y, x0.z, x0.w, x1.x, x1.y, x1.z, x1.w};
        u16x8 o;
#pragma unroll
        for (int j = 0; j < 8; ++j) {
            float s = frcp(1.0f + __expf(-v[j]));
            s = fminf(fmaxf(s, EPSF), 1.0f - EPSF);
            o[j] = f2bf(s);
        }
        *reinterpret_cast<u16x8*>(probs + i) = o;
    } else {
        int wave = threadIdx.x >> 6;
        int lane = threadIdx.x & 63;
        int m = (b - 900) * 4 + wave;               // [0,2000)
        float4 v = reinterpret_cast<const float4*>(lab)[m * (TT / 4) + lane];
        float s = v.x + v.y + v.z + v.w;
#pragma unroll
        for (int off = 32; off > 0; off >>= 1) s += __shfl_down(s, off);
        float inv = frcp(__shfl(s, 0) + EPSF);
        u16x4 o;
        o[0] = f2bf(v.x * inv); o[1] = f2bf(v.y * inv);
        o[2] = f2bf(v.z * inv); o[3] = f2bf(v.w * inv);
        *reinterpret_cast<u16x4*>(nlab + m * TT + lane * 4) = o;
    }
}

// ---------------- Kernel 2: MFMA cost, FULL-K REGISTER PREFETCH ----------------
// 64x64 per 256-thread block (4 waves 2x2, each wave 32x32 via 2x2 mfma_16x16x32).
// All 32 A/B fragment loads + all epilogue box loads are issued before any MFMA:
// one memory round-trip per wave instead of a serialized load->wait->mfma chain.
// 1D grid with XCD slab swizzle: XCD c owns a contiguous x-slab of A + all of B
// (per-XCD working set ~1.5MB -> fits 4MB L2).
constexpr int NTX = 113, NTY = 32;                  // 64-row tiles: 113 x 32 = 3616

__global__ __launch_bounds__(256, 2) void cost_mfma_kernel(
    const unsigned short* __restrict__ A,   // probs bf16 [NP][TT]
    const unsigned short* __restrict__ B,   // nlab  bf16 [MT][TT]
    const float* __restrict__ pbox,         // [NP][4] cxcywh
    const float* __restrict__ tbox,         // [MT][4] cxcywh
    float* __restrict__ out)                // [NP][MT] fp32
{
    // XCD slab swizzle: dispatch round-robins linear id over 8 XCDs.
    // l = (n%8)*452 + n/8 gives XCD c the contiguous l-range [452c, 452c+452),
    // i.e. x-tiles [14.1c, 14.1(c+1)) with y fastest -> A-slab + all-B per XCD.
    int n = blockIdx.x;
    int l = (n & 7) * 452 + (n >> 3);
    int tx = l >> 5;                 // l / 32  (0..112)
    int ty = l & 31;                 // l % 32
    const int n0 = tx * 64;
    const int m0 = ty * 64;

    const int tid = threadIdx.x;
    const int lane = tid & 63, wave = tid >> 6;
    const int wr = wave & 1, wc = wave >> 1;        // wave's 32x32 quadrant
    const int fr = lane & 15, quad = lane >> 4;     // fragment row / k-quad

    // ---- issue ALL GEMM loads ----
    bf16x8 af[2][8], bg[2][8];
#pragma unroll
    for (int t = 0; t < 2; ++t) {
        int gn = n0 + wr * 32 + t * 16 + fr; if (gn > NP - 1) gn = NP - 1;
        const unsigned short* pa = A + gn * TT + quad * 8;
        int gm = m0 + wc * 32 + t * 16 + fr; if (gm > MT - 1) gm = MT - 1;
        const unsigned short* pb = B + gm * TT + quad * 8;
#pragma unroll
        for (int kk = 0; kk < 8; ++kk) {
            af[t][kk] = *reinterpret_cast<const bf16x8*>(pa + kk * 32);
            bg[t][kk] = *reinterpret_cast<const bf16x8*>(pb + kk * 32);
        }
    }

    // ---- issue epilogue box loads (overlap their latency with the MFMAs) ----
    float4 tb[2]; int mj[2]; bool mv[2];
#pragma unroll
    for (int tj = 0; tj < 2; ++tj) {
        int gm = m0 + wc * 32 + tj * 16 + fr;
        mv[tj] = gm < MT; mj[tj] = gm;
        int g = mv[tj] ? gm : MT - 1;
        tb[tj] = *reinterpret_cast<const float4*>(&tbox[g * 4]);
    }
    float4 pbv[2][4]; int pr[2][4];
#pragma unroll
    for (int ti = 0; ti < 2; ++ti)
#pragma unroll
        for (int r = 0; r < 4; ++r) {
            int p = n0 + wr * 32 + ti * 16 + quad * 4 + r;   // C/D: row = quad*4 + reg
            pr[ti][r] = p;
            int g = p < NP ? p : NP - 1;
            pbv[ti][r] = *reinterpret_cast<const float4*>(&pbox[g * 4]);
        }

    // ---- MFMAs consume loads in issue order (progressive vmcnt waits) ----
    f32x4 acc[2][2] = {};
#pragma unroll
    for (int kk = 0; kk < 8; ++kk)
#pragma unroll
        for (int ti = 0; ti < 2; ++ti)
#pragma unroll
            for (int tj = 0; tj < 2; ++tj)
                acc[ti][tj] = __builtin_amdgcn_mfma_f32_16x16x32_bf16(
                    af[ti][kk], bg[tj][kk], acc[ti][tj], 0, 0, 0);

    // ---- epilogue: box costs from prefetched registers ----
    float bcx[2], bcy[2], bww[2], bhh[2], bx1[2], by1[2], bx2[2], by2[2], areaB[2];
#pragma unroll
    for (int tj = 0; tj < 2; ++tj) {
        float4 b = tb[tj];
        bcx[tj] = b.x; bcy[tj] = b.y; bww[tj] = b.z; bhh[tj] = b.w;
        bx1[tj] = b.x - 0.5f * b.z; by1[tj] = b.y - 0.5f * b.w;
        bx2[tj] = b.x + 0.5f * b.z; by2[tj] = b.y + 0.5f * b.w;
        areaB[tj] = (bx2[tj] - bx1[tj]) * (by2[tj] - by1[tj]);
    }

#pragma unroll
    for (int ti = 0; ti < 2; ++ti) {
#pragma unroll
        for (int r = 0; r < 4; ++r) {
            int p = pr[ti][r];
            if (p >= NP) continue;
            float4 pb4 = pbv[ti][r];
            float ax1 = pb4.x - 0.5f * pb4.z, ay1 = pb4.y - 0.5f * pb4.w;
            float ax2 = pb4.x + 0.5f * pb4.z, ay2 = pb4.y + 0.5f * pb4.w;
            float areaA = (ax2 - ax1) * (ay2 - ay1);
#pragma unroll
            for (int tj = 0; tj < 2; ++tj) {
                if (!mv[tj]) continue;
                float l1 = fabsf(pb4.x - bcx[tj]) + fabsf(pb4.y - bcy[tj]) +
                           fabsf(pb4.z - bww[tj]) + fabsf(pb4.w - bhh[tj]);
                float ltx = fmaxf(ax1, bx1[tj]), lty = fmaxf(ay1, by1[tj]);
                float rbx = fminf(ax2, bx2[tj]), rby = fminf(ay2, by2[tj]);
                float iw = fmaxf(rbx - ltx, 0.0f), ih = fmaxf(rby - lty, 0.0f);
                float inter = iw * ih;
                float uni = areaA + areaB[tj] - inter;
                float iou = inter * frcp(uni + EPSF);
                float ex1 = fminf(ax1, bx1[tj]), ey1 = fminf(ay1, by1[tj]);
                float ex2 = fmaxf(ax2, bx2[tj]), ey2 = fmaxf(ay2, by2[tj]);
                float ew = fmaxf(ex2 - ex1, 0.0f), eh = fmaxf(ey2 - ey1, 0.0f);
                float areaE = ew * eh;
                float giou = iou - (areaE - uni) * frcp(areaE + EPSF);
                float res = 5.0f * l1 - acc[ti][tj][r] - 2.0f * fmaxf(giou, -1.0f);
                out[p * MT + mj[tj]] = res;
            }
        }
    }
}

extern "C" void kernel_launch(void* const* d_in, const int* in_sizes, int n_in,
                              void* d_out, int out_size, void* d_ws, size_t ws_size,
                              hipStream_t stream) {
    const float* pred_logits = (const float*)d_in[0];  // [8,900,256]
    const float* pred_boxes  = (const float*)d_in[1];  // [8,900,4]
    const float* tgt_boxes   = (const float*)d_in[2];  // [2000,4]
    const float* tgt_labels  = (const float*)d_in[3];  // [2000,256]
    float* out = (float*)d_out;                        // [7200,2000]

    unsigned short* probs = (unsigned short*)d_ws;     // 7200*256 bf16 (3.7 MB)
    unsigned short* nlab  = probs + NP * TT;           // 2000*256 bf16 (1.0 MB)

    prep_kernel<<<900 + 500, 256, 0, stream>>>(pred_logits, tgt_labels, probs, nlab);

    cost_mfma_kernel<<<NTX * NTY, 256, 0, stream>>>(probs, nlab, pred_boxes, tgt_boxes, out);
}

// Round 7
// 105.901 us; speedup vs baseline: 1.3137x; 1.3137x over previous
//
#include <hip/hip_runtime.h>
#include <math.h>

#define EPSF 1e-6f

typedef __attribute__((ext_vector_type(8))) short bf16x8;   // 8 bf16 = 4 VGPR (MFMA A/B frag)
typedef __attribute__((ext_vector_type(4))) float f32x4;    // MFMA C/D frag
typedef __attribute__((ext_vector_type(4))) unsigned short u16x4;
typedef __attribute__((ext_vector_type(8))) unsigned short u16x8;

constexpr int TT = 256, MT = 2000, NP = 7200;

static __device__ __forceinline__ unsigned short f2bf(float f) {
    unsigned int u = __float_as_uint(f);
    u += 0x7FFFu + ((u >> 16) & 1u);
    return (unsigned short)(u >> 16);
}
static __device__ __forceinline__ float frcp(float x) { return __builtin_amdgcn_rcpf(x); }

// ---------------- Kernel 1: fused prep ----------------
__global__ __launch_bounds__(256) void prep_kernel(const float* __restrict__ logits,
                                                   const float* __restrict__ lab,
                                                   unsigned short* __restrict__ probs,
                                                   unsigned short* __restrict__ nlab) {
    int b = blockIdx.x;
    if (b < 900) {
        int i = (b * 256 + threadIdx.x) * 8;
        float4 x0 = *reinterpret_cast<const float4*>(logits + i);
        float4 x1 = *reinterpret_cast<const float4*>(logits + i + 4);
        float v[8] = {x0.x, x0.y, x0.z, x0.w, x1.x, x1.y, x1.z, x1.w};
        u16x8 o;
#pragma unroll
        for (int j = 0; j < 8; ++j) {
            float s = frcp(1.0f + __expf(-v[j]));
            s = fminf(fmaxf(s, EPSF), 1.0f - EPSF);
            o[j] = f2bf(s);
        }
        *reinterpret_cast<u16x8*>(probs + i) = o;
    } else {
        int wave = threadIdx.x >> 6;
        int lane = threadIdx.x & 63;
        int m = (b - 900) * 4 + wave;               // [0,2000)
        float4 v = reinterpret_cast<const float4*>(lab)[m * (TT / 4) + lane];
        float s = v.x + v.y + v.z + v.w;
#pragma unroll
        for (int off = 32; off > 0; off >>= 1) s += __shfl_down(s, off);
        float inv = frcp(__shfl(s, 0) + EPSF);
        u16x4 o;
        o[0] = f2bf(v.x * inv); o[1] = f2bf(v.y * inv);
        o[2] = f2bf(v.z * inv); o[3] = f2bf(v.w * inv);
        *reinterpret_cast<u16x4*>(nlab + m * TT + lane * 4) = o;
    }
}

// ---------------- Kernel 2: LDS-staged MFMA cost matrix ----------------
// 64x64 per 256-thread block (4 waves 2x2, each wave 32x32 via 2x2 mfma_16x16x32).
// K=256 staged in 2 chunks of 128 via per-thread batched loads -> LDS:
// exactly 2 global round-trips per block (vs per-wave load->mfma chains that the
// compiler serializes when fragments are fetched from global directly — R6: VGPR=48).
// XCD slab swizzle kept from R6 (FETCH 32->6MB confirmed).
constexpr int NTX = 113, NTY = 32;                  // 3616 tiles
constexpr int LDR = 132;                            // LDS row stride (128 + 4 elems pad)

__global__ __launch_bounds__(256, 3) void cost_mfma_kernel(
    const unsigned short* __restrict__ A,   // probs bf16 [NP][TT]
    const unsigned short* __restrict__ B,   // nlab  bf16 [MT][TT]
    const float* __restrict__ pbox,         // [NP][4] cxcywh
    const float* __restrict__ tbox,         // [MT][4] cxcywh
    float* __restrict__ out)                // [NP][MT] fp32
{
    __shared__ __align__(16) unsigned short As[64 * LDR];   // 16.9 KB
    __shared__ __align__(16) unsigned short Bs[64 * LDR];   // 16.9 KB

    // XCD slab swizzle (R6): XCD c gets contiguous l-range -> A-slab + all-B in its L2.
    int n = blockIdx.x;
    int l = (n & 7) * 452 + (n >> 3);
    const int n0 = (l >> 5) * 64;
    const int m0 = (l & 31) * 64;

    const int tid = threadIdx.x;
    const int lane = tid & 63, wave = tid >> 6;
    const int wr = wave & 1, wc = wave >> 1;        // wave's 32x32 quadrant
    const int fr = lane & 15, quad = lane >> 4;     // fragment row / k-quad

    // Staging assignment: linear chunk id = tid + 256*i, row = id>>4, ch = id&15
    // (16 consecutive lanes cover one row's 16x16B = 256B contiguous global).
    const int s_row = tid >> 4;          // +16 per i
    const int s_ch  = tid & 15;

    // Epilogue box prefetch (issued early; L1/L2 resident, overlaps staging).
    float4 tb[2]; int mj[2]; bool mv[2];
#pragma unroll
    for (int tj = 0; tj < 2; ++tj) {
        int gm = m0 + wc * 32 + tj * 16 + fr;
        mv[tj] = gm < MT; mj[tj] = gm;
        int g = mv[tj] ? gm : MT - 1;
        tb[tj] = *reinterpret_cast<const float4*>(&tbox[g * 4]);
    }
    float4 pbv[2][4]; int pr[2][4];
#pragma unroll
    for (int ti = 0; ti < 2; ++ti)
#pragma unroll
        for (int r = 0; r < 4; ++r) {
            int p = n0 + wr * 32 + ti * 16 + quad * 4 + r;   // C/D: row = quad*4 + reg
            pr[ti][r] = p;
            int g = p < NP ? p : NP - 1;
            pbv[ti][r] = *reinterpret_cast<const float4*>(&pbox[g * 4]);
        }

    f32x4 acc[2][2] = {};

#pragma unroll
    for (int k0 = 0; k0 < TT; k0 += 128) {
        if (k0) __syncthreads();                      // protect LDS reuse
        // ---- batched staging: 8 independent global loads, then 8 LDS writes ----
        bf16x8 sa[4], sb[4];
#pragma unroll
        for (int i = 0; i < 4; ++i) {
            int row = s_row + i * 16;
            int gn = n0 + row; if (gn > NP - 1) gn = NP - 1;
            sa[i] = *reinterpret_cast<const bf16x8*>(&A[gn * TT + k0 + s_ch * 8]);
            int gm = m0 + row; if (gm > MT - 1) gm = MT - 1;
            sb[i] = *reinterpret_cast<const bf16x8*>(&B[gm * TT + k0 + s_ch * 8]);
        }
#pragma unroll
        for (int i = 0; i < 4; ++i) {
            int row = s_row + i * 16;
            *reinterpret_cast<bf16x8*>(&As[row * LDR + s_ch * 8]) = sa[i];
            *reinterpret_cast<bf16x8*>(&Bs[row * LDR + s_ch * 8]) = sb[i];
        }
        __syncthreads();
        // ---- MFMA loop: LDS-only operands ----
#pragma unroll
        for (int kk = 0; kk < 4; ++kk) {
            bf16x8 af[2], bg[2];
#pragma unroll
            for (int t = 0; t < 2; ++t) {
                af[t] = *reinterpret_cast<const bf16x8*>(
                    &As[(wr * 32 + t * 16 + fr) * LDR + kk * 32 + quad * 8]);
                bg[t] = *reinterpret_cast<const bf16x8*>(
                    &Bs[(wc * 32 + t * 16 + fr) * LDR + kk * 32 + quad * 8]);
            }
#pragma unroll
            for (int ti = 0; ti < 2; ++ti)
#pragma unroll
                for (int tj = 0; tj < 2; ++tj)
                    acc[ti][tj] = __builtin_amdgcn_mfma_f32_16x16x32_bf16(
                        af[ti], bg[tj], acc[ti][tj], 0, 0, 0);
        }
    }

    // -------- epilogue from prefetched registers --------
    float bcx[2], bcy[2], bww[2], bhh[2], bx1[2], by1[2], bx2[2], by2[2], areaB[2];
#pragma unroll
    for (int tj = 0; tj < 2; ++tj) {
        float4 b = tb[tj];
        bcx[tj] = b.x; bcy[tj] = b.y; bww[tj] = b.z; bhh[tj] = b.w;
        bx1[tj] = b.x - 0.5f * b.z; by1[tj] = b.y - 0.5f * b.w;
        bx2[tj] = b.x + 0.5f * b.z; by2[tj] = b.y + 0.5f * b.w;
        areaB[tj] = (bx2[tj] - bx1[tj]) * (by2[tj] - by1[tj]);
    }

#pragma unroll
    for (int ti = 0; ti < 2; ++ti) {
#pragma unroll
        for (int r = 0; r < 4; ++r) {
            int p = pr[ti][r];
            if (p >= NP) continue;
            float4 pb4 = pbv[ti][r];
            float ax1 = pb4.x - 0.5f * pb4.z, ay1 = pb4.y - 0.5f * pb4.w;
            float ax2 = pb4.x + 0.5f * pb4.z, ay2 = pb4.y + 0.5f * pb4.w;
            float areaA = (ax2 - ax1) * (ay2 - ay1);
#pragma unroll
            for (int tj = 0; tj < 2; ++tj) {
                if (!mv[tj]) continue;
                float l1 = fabsf(pb4.x - bcx[tj]) + fabsf(pb4.y - bcy[tj]) +
                           fabsf(pb4.z - bww[tj]) + fabsf(pb4.w - bhh[tj]);
                float ltx = fmaxf(ax1, bx1[tj]), lty = fmaxf(ay1, by1[tj]);
                float rbx = fminf(ax2, bx2[tj]), rby = fminf(ay2, by2[tj]);
                float iw = fmaxf(rbx - ltx, 0.0f), ih = fmaxf(rby - lty, 0.0f);
                float inter = iw * ih;
                float uni = areaA + areaB[tj] - inter;
                float iou = inter * frcp(uni + EPSF);
                float ex1 = fminf(ax1, bx1[tj]), ey1 = fminf(ay1, by1[tj]);
                float ex2 = fmaxf(ax2, bx2[tj]), ey2 = fmaxf(ay2, by2[tj]);
                float ew = fmaxf(ex2 - ex1, 0.0f), eh = fmaxf(ey2 - ey1, 0.0f);
                float areaE = ew * eh;
                float giou = iou - (areaE - uni) * frcp(areaE + EPSF);
                float res = 5.0f * l1 - acc[ti][tj][r] - 2.0f * fmaxf(giou, -1.0f);
                out[p * MT + mj[tj]] = res;
            }
        }
    }
}

extern "C" void kernel_launch(void* const* d_in, const int* in_sizes, int n_in,
                              void* d_out, int out_size, void* d_ws, size_t ws_size,
                              hipStream_t stream) {
    const float* pred_logits = (const float*)d_in[0];  // [8,900,256]
    const float* pred_boxes  = (const float*)d_in[1];  // [8,900,4]
    const float* tgt_boxes   = (const float*)d_in[2];  // [2000,4]
    const float* tgt_labels  = (const float*)d_in[3];  // [2000,256]
    float* out = (float*)d_out;                        // [7200,2000]

    unsigned short* probs = (unsigned short*)d_ws;     // 7200*256 bf16 (3.7 MB)
    unsigned short* nlab  = probs + NP * TT;           // 2000*256 bf16 (1.0 MB)

    prep_kernel<<<900 + 500, 256, 0, stream>>>(pred_logits, tgt_labels, probs, nlab);

    cost_mfma_kernel<<<NTX * NTY, 256, 0, stream>>>(probs, nlab, pred_boxes, tgt_boxes, out);
}

// Round 8
// 104.025 us; speedup vs baseline: 1.3374x; 1.0180x over previous
//
#include <hip/hip_runtime.h>
#include <math.h>

#define EPSF 1e-6f

typedef __attribute__((ext_vector_type(8))) short bf16x8;   // 8 bf16 = 4 VGPR (MFMA A/B frag)
typedef __attribute__((ext_vector_type(4))) float f32x4;    // MFMA C/D frag
typedef __attribute__((ext_vector_type(4))) unsigned short u16x4;
typedef __attribute__((ext_vector_type(8))) unsigned short u16x8;

constexpr int TT = 256, MT = 2000, NP = 7200;

static __device__ __forceinline__ unsigned short f2bf(float f) {
    unsigned int u = __float_as_uint(f);
    u += 0x7FFFu + ((u >> 16) & 1u);
    return (unsigned short)(u >> 16);
}
static __device__ __forceinline__ float frcp(float x) { return __builtin_amdgcn_rcpf(x); }

// ---------------- Kernel 1: fused prep ----------------
__global__ __launch_bounds__(256) void prep_kernel(const float* __restrict__ logits,
                                                   const float* __restrict__ lab,
                                                   unsigned short* __restrict__ probs,
                                                   unsigned short* __restrict__ nlab) {
    int b = blockIdx.x;
    if (b < 900) {
        int i = (b * 256 + threadIdx.x) * 8;
        float4 x0 = *reinterpret_cast<const float4*>(logits + i);
        float4 x1 = *reinterpret_cast<const float4*>(logits + i + 4);
        float v[8] = {x0.x, x0.y, x0.z, x0.w, x1.x, x1.y, x1.z, x1.w};
        u16x8 o;
#pragma unroll
        for (int j = 0; j < 8; ++j) {
            float s = frcp(1.0f + __expf(-v[j]));
            s = fminf(fmaxf(s, EPSF), 1.0f - EPSF);
            o[j] = f2bf(s);
        }
        *reinterpret_cast<u16x8*>(probs + i) = o;
    } else {
        int wave = threadIdx.x >> 6;
        int lane = threadIdx.x & 63;
        int m = (b - 900) * 4 + wave;               // [0,2000)
        float4 v = reinterpret_cast<const float4*>(lab)[m * (TT / 4) + lane];
        float s = v.x + v.y + v.z + v.w;
#pragma unroll
        for (int off = 32; off > 0; off >>= 1) s += __shfl_down(s, off);
        float inv = frcp(__shfl(s, 0) + EPSF);
        u16x4 o;
        o[0] = f2bf(v.x * inv); o[1] = f2bf(v.y * inv);
        o[2] = f2bf(v.z * inv); o[3] = f2bf(v.w * inv);
        *reinterpret_cast<u16x4*>(nlab + m * TT + lane * 4) = o;
    }
}

// ---------------- Kernel 2: pipelined LDS-staged MFMA cost matrix ----------------
// 64x64 per 256-thread block (4 waves 2x2, each wave 32x32 via 2x2 mfma_16x16x32).
// K=256 in 2 chunks of 128. Chunk1's global loads are issued BEFORE chunk0's MFMA
// phase, so their latency hides behind MFMA+LDS work: critical path = 1 global RT.
// Single LDS buffer (33.8 KB) + __launch_bounds__(256,4) -> 4 blocks/CU resident.
// XCD slab swizzle kept (R6: FETCH 32->6MB confirmed).
constexpr int NTX = 113, NTY = 32;                  // 3616 tiles
constexpr int LDR = 132;                            // LDS row stride (128 + 4 elems pad)

__global__ __launch_bounds__(256, 4) void cost_mfma_kernel(
    const unsigned short* __restrict__ A,   // probs bf16 [NP][TT]
    const unsigned short* __restrict__ B,   // nlab  bf16 [MT][TT]
    const float* __restrict__ pbox,         // [NP][4] cxcywh
    const float* __restrict__ tbox,         // [MT][4] cxcywh
    float* __restrict__ out)                // [NP][MT] fp32
{
    __shared__ __align__(16) unsigned short As[64 * LDR];   // 16.9 KB
    __shared__ __align__(16) unsigned short Bs[64 * LDR];   // 16.9 KB

    // XCD slab swizzle: XCD c gets contiguous l-range -> A-slab + all-B in its L2.
    int n = blockIdx.x;
    int l = (n & 7) * 452 + (n >> 3);
    const int n0 = (l >> 5) * 64;
    const int m0 = (l & 31) * 64;

    const int tid = threadIdx.x;
    const int lane = tid & 63, wave = tid >> 6;
    const int wr = wave & 1, wc = wave >> 1;        // wave's 32x32 quadrant
    const int fr = lane & 15, quad = lane >> 4;     // fragment row / k-quad

    const int s_row = tid >> 4;          // staging row base (+16 per i)
    const int s_ch  = tid & 15;          // 16 lanes cover one row's 256B

    // Clamped staging row indices (reused for both chunks).
    int gn4[4], gm4[4];
#pragma unroll
    for (int i = 0; i < 4; ++i) {
        int row = s_row + i * 16;
        int gn = n0 + row; gn4[i] = gn > NP - 1 ? NP - 1 : gn;
        int gm = m0 + row; gm4[i] = gm > MT - 1 ? MT - 1 : gm;
    }

    // Epilogue box prefetch (issued early, lands during staging).
    float4 tb[2]; int mj[2]; bool mv[2];
#pragma unroll
    for (int tj = 0; tj < 2; ++tj) {
        int gm = m0 + wc * 32 + tj * 16 + fr;
        mv[tj] = gm < MT; mj[tj] = gm;
        int g = mv[tj] ? gm : MT - 1;
        tb[tj] = *reinterpret_cast<const float4*>(&tbox[g * 4]);
    }
    float4 pbv[2][4]; int pr[2][4];
#pragma unroll
    for (int ti = 0; ti < 2; ++ti)
#pragma unroll
        for (int r = 0; r < 4; ++r) {
            int p = n0 + wr * 32 + ti * 16 + quad * 4 + r;   // C/D: row = quad*4 + reg
            pr[ti][r] = p;
            int g = p < NP ? p : NP - 1;
            pbv[ti][r] = *reinterpret_cast<const float4*>(&pbox[g * 4]);
        }

    // ---- stage chunk 0 ----
    bf16x8 sa[4], sb[4];
#pragma unroll
    for (int i = 0; i < 4; ++i) {
        sa[i] = *reinterpret_cast<const bf16x8*>(&A[gn4[i] * TT + s_ch * 8]);
        sb[i] = *reinterpret_cast<const bf16x8*>(&B[gm4[i] * TT + s_ch * 8]);
    }
#pragma unroll
    for (int i = 0; i < 4; ++i) {
        int row = s_row + i * 16;
        *reinterpret_cast<bf16x8*>(&As[row * LDR + s_ch * 8]) = sa[i];
        *reinterpret_cast<bf16x8*>(&Bs[row * LDR + s_ch * 8]) = sb[i];
    }
    __syncthreads();

    // ---- issue chunk 1 global loads (fly during chunk-0 MFMA phase) ----
    bf16x8 sa1[4], sb1[4];
#pragma unroll
    for (int i = 0; i < 4; ++i) {
        sa1[i] = *reinterpret_cast<const bf16x8*>(&A[gn4[i] * TT + 128 + s_ch * 8]);
        sb1[i] = *reinterpret_cast<const bf16x8*>(&B[gm4[i] * TT + 128 + s_ch * 8]);
    }

    f32x4 acc[2][2] = {};
    // ---- MFMA on chunk 0 ----
#pragma unroll
    for (int kk = 0; kk < 4; ++kk) {
        bf16x8 af[2], bg[2];
#pragma unroll
        for (int t = 0; t < 2; ++t) {
            af[t] = *reinterpret_cast<const bf16x8*>(
                &As[(wr * 32 + t * 16 + fr) * LDR + kk * 32 + quad * 8]);
            bg[t] = *reinterpret_cast<const bf16x8*>(
                &Bs[(wc * 32 + t * 16 + fr) * LDR + kk * 32 + quad * 8]);
        }
#pragma unroll
        for (int ti = 0; ti < 2; ++ti)
#pragma unroll
            for (int tj = 0; tj < 2; ++tj)
                acc[ti][tj] = __builtin_amdgcn_mfma_f32_16x16x32_bf16(
                    af[ti], bg[tj], acc[ti][tj], 0, 0, 0);
    }
    __syncthreads();   // all waves done reading chunk 0

    // ---- write chunk 1 into LDS (loads have been in flight) ----
#pragma unroll
    for (int i = 0; i < 4; ++i) {
        int row = s_row + i * 16;
        *reinterpret_cast<bf16x8*>(&As[row * LDR + s_ch * 8]) = sa1[i];
        *reinterpret_cast<bf16x8*>(&Bs[row * LDR + s_ch * 8]) = sb1[i];
    }
    __syncthreads();

    // ---- MFMA on chunk 1 ----
#pragma unroll
    for (int kk = 0; kk < 4; ++kk) {
        bf16x8 af[2], bg[2];
#pragma unroll
        for (int t = 0; t < 2; ++t) {
            af[t] = *reinterpret_cast<const bf16x8*>(
                &As[(wr * 32 + t * 16 + fr) * LDR + kk * 32 + quad * 8]);
            bg[t] = *reinterpret_cast<const bf16x8*>(
                &Bs[(wc * 32 + t * 16 + fr) * LDR + kk * 32 + quad * 8]);
        }
#pragma unroll
        for (int ti = 0; ti < 2; ++ti)
#pragma unroll
            for (int tj = 0; tj < 2; ++tj)
                acc[ti][tj] = __builtin_amdgcn_mfma_f32_16x16x32_bf16(
                    af[ti], bg[tj], acc[ti][tj], 0, 0, 0);
    }

    // -------- epilogue from prefetched registers --------
    float bcx[2], bcy[2], bww[2], bhh[2], bx1[2], by1[2], bx2[2], by2[2], areaB[2];
#pragma unroll
    for (int tj = 0; tj < 2; ++tj) {
        float4 b = tb[tj];
        bcx[tj] = b.x; bcy[tj] = b.y; bww[tj] = b.z; bhh[tj] = b.w;
        bx1[tj] = b.x - 0.5f * b.z; by1[tj] = b.y - 0.5f * b.w;
        bx2[tj] = b.x + 0.5f * b.z; by2[tj] = b.y + 0.5f * b.w;
        areaB[tj] = (bx2[tj] - bx1[tj]) * (by2[tj] - by1[tj]);
    }

#pragma unroll
    for (int ti = 0; ti < 2; ++ti) {
#pragma unroll
        for (int r = 0; r < 4; ++r) {
            int p = pr[ti][r];
            if (p >= NP) continue;
            float4 pb4 = pbv[ti][r];
            float ax1 = pb4.x - 0.5f * pb4.z, ay1 = pb4.y - 0.5f * pb4.w;
            float ax2 = pb4.x + 0.5f * pb4.z, ay2 = pb4.y + 0.5f * pb4.w;
            float areaA = (ax2 - ax1) * (ay2 - ay1);
#pragma unroll
            for (int tj = 0; tj < 2; ++tj) {
                if (!mv[tj]) continue;
                float l1 = fabsf(pb4.x - bcx[tj]) + fabsf(pb4.y - bcy[tj]) +
                           fabsf(pb4.z - bww[tj]) + fabsf(pb4.w - bhh[tj]);
                float ltx = fmaxf(ax1, bx1[tj]), lty = fmaxf(ay1, by1[tj]);
                float rbx = fminf(ax2, bx2[tj]), rby = fminf(ay2, by2[tj]);
                float iw = fmaxf(rbx - ltx, 0.0f), ih = fmaxf(rby - lty, 0.0f);
                float inter = iw * ih;
                float uni = areaA + areaB[tj] - inter;
                float iou = inter * frcp(uni + EPSF);
                float ex1 = fminf(ax1, bx1[tj]), ey1 = fminf(ay1, by1[tj]);
                float ex2 = fmaxf(ax2, bx2[tj]), ey2 = fmaxf(ay2, by2[tj]);
                float ew = fmaxf(ex2 - ex1, 0.0f), eh = fmaxf(ey2 - ey1, 0.0f);
                float areaE = ew * eh;
                float giou = iou - (areaE - uni) * frcp(areaE + EPSF);
                float res = 5.0f * l1 - acc[ti][tj][r] - 2.0f * fmaxf(giou, -1.0f);
                out[p * MT + mj[tj]] = res;
            }
        }
    }
}

extern "C" void kernel_launch(void* const* d_in, const int* in_sizes, int n_in,
                              void* d_out, int out_size, void* d_ws, size_t ws_size,
                              hipStream_t stream) {
    const float* pred_logits = (const float*)d_in[0];  // [8,900,256]
    const float* pred_boxes  = (const float*)d_in[1];  // [8,900,4]
    const float* tgt_boxes   = (const float*)d_in[2];  // [2000,4]
    const float* tgt_labels  = (const float*)d_in[3];  // [2000,256]
    float* out = (float*)d_out;                        // [7200,2000]

    unsigned short* probs = (unsigned short*)d_ws;     // 7200*256 bf16 (3.7 MB)
    unsigned short* nlab  = probs + NP * TT;           // 2000*256 bf16 (1.0 MB)

    prep_kernel<<<900 + 500, 256, 0, stream>>>(pred_logits, tgt_labels, probs, nlab);

    cost_mfma_kernel<<<NTX * NTY, 256, 0, stream>>>(probs, nlab, pred_boxes, tgt_boxes, out);
}